// Round 1
// baseline (97.318 us; speedup 1.0000x reference)
//
#include <hip/hip_runtime.h>
#include <hip/hip_bf16.h>

// out[e] = dot(h[src[e]], h[dst[e]]), D_FEAT=16 fp32.
// One thread per edge; two gathered 64B rows via float4 loads; grid-stride.
__global__ __launch_bounds__(256) void edge_dot_kernel(
    const float4* __restrict__ h,      // [N_NODES*4] float4 (row = 4 x float4)
    const int* __restrict__ src,       // [E]
    const int* __restrict__ dst,       // [E]
    float* __restrict__ out,           // [E]
    int E)
{
    int idx = blockIdx.x * blockDim.x + threadIdx.x;
    int stride = gridDim.x * blockDim.x;
    for (int e = idx; e < E; e += stride) {
        int s = src[e];
        int d = dst[e];
        const float4* hs = h + (size_t)s * 4;
        const float4* hd = h + (size_t)d * 4;
        float acc = 0.0f;
#pragma unroll
        for (int k = 0; k < 4; ++k) {
            float4 a = hs[k];
            float4 b = hd[k];
            acc += a.x * b.x + a.y * b.y + a.z * b.z + a.w * b.w;
        }
        out[e] = acc;
    }
}

extern "C" void kernel_launch(void* const* d_in, const int* in_sizes, int n_in,
                              void* d_out, int out_size, void* d_ws, size_t ws_size,
                              hipStream_t stream) {
    const float* h   = (const float*)d_in[0];   // [N_NODES, 16] fp32
    const int*   src = (const int*)d_in[1];     // [E] (harness: integer -> int32)
    const int*   dst = (const int*)d_in[2];     // [E]
    float*       out = (float*)d_out;           // [E, 1] fp32

    const int E = in_sizes[1];

    const int block = 256;
    // Grid-stride: cap blocks so each thread gets ~6 edges of ILP.
    int grid = (E + block - 1) / block;
    if (grid > 2048) grid = 2048;

    edge_dot_kernel<<<grid, block, 0, stream>>>(
        (const float4*)h, src, dst, out, E);
}

// Round 2
// 44.526 us; speedup vs baseline: 2.1857x; 2.1857x over previous
//
#include <hip/hip_runtime.h>
#include <hip/hip_bf16.h>
#include <hip/hip_fp16.h>

// Phase 1: convert h (fp32, [N,16]) -> fp16 table in workspace ([N,16] halfs,
// 32 B/row). 3.2 MB fits in each XCD's 4 MB L2, so the random row gathers in
// phase 2 become L2 hits instead of thrashing (fp32 table is 6.4 MB > 4 MB).
__global__ __launch_bounds__(256) void convert_h_fp16(
    const float4* __restrict__ h4,   // [N*4] float4
    uint4* __restrict__ hh,          // [N*2] uint4 (8 halfs each)
    int n_out)                       // N*2
{
    int i = blockIdx.x * blockDim.x + threadIdx.x;
    if (i >= n_out) return;
    float4 a = h4[2 * i];
    float4 b = h4[2 * i + 1];
    __half2 p[4];
    p[0] = __floats2half2_rn(a.x, a.y);
    p[1] = __floats2half2_rn(a.z, a.w);
    p[2] = __floats2half2_rn(b.x, b.y);
    p[3] = __floats2half2_rn(b.z, b.w);
    hh[i] = *reinterpret_cast<const uint4*>(p);
}

__device__ __forceinline__ float dot2u(unsigned a, unsigned b) {
    __half2 ha = *reinterpret_cast<const __half2*>(&a);
    __half2 hb = *reinterpret_cast<const __half2*>(&b);
    float2 fa = __half22float2(ha);
    float2 fb = __half22float2(hb);
    return fa.x * fb.x + fa.y * fb.y;
}

__device__ __forceinline__ float dot16(const uint4* __restrict__ hh, int s, int d) {
    uint4 a0 = hh[(size_t)s * 2];
    uint4 a1 = hh[(size_t)s * 2 + 1];
    uint4 b0 = hh[(size_t)d * 2];
    uint4 b1 = hh[(size_t)d * 2 + 1];
    float acc = dot2u(a0.x, b0.x);
    acc += dot2u(a0.y, b0.y);
    acc += dot2u(a0.z, b0.z);
    acc += dot2u(a0.w, b0.w);
    acc += dot2u(a1.x, b1.x);
    acc += dot2u(a1.y, b1.y);
    acc += dot2u(a1.z, b1.z);
    acc += dot2u(a1.w, b1.w);
    return acc;
}

// Phase 2: one thread per 4 edges. int4 index loads, float4 result store,
// 8 independent 16B row-gathers in flight per thread.
__global__ __launch_bounds__(256) void edge_dot_fp16(
    const uint4* __restrict__ hh,    // [N*2]
    const int4* __restrict__ src4,   // [E/4]
    const int4* __restrict__ dst4,   // [E/4]
    float4* __restrict__ out4,       // [E/4]
    int nq,                          // E/4
    const int* __restrict__ src,     // scalar views for tail
    const int* __restrict__ dst,
    float* __restrict__ out,
    int E)
{
    int i = blockIdx.x * blockDim.x + threadIdx.x;
    int stride = gridDim.x * blockDim.x;
    for (int q = i; q < nq; q += stride) {
        int4 s = src4[q];
        int4 d = dst4[q];
        float4 r;
        r.x = dot16(hh, s.x, d.x);
        r.y = dot16(hh, s.y, d.y);
        r.z = dot16(hh, s.z, d.z);
        r.w = dot16(hh, s.w, d.w);
        out4[q] = r;
    }
    // tail (E % 4 != 0) — handled by thread 0 of block 0
    if (i == 0) {
        for (int e = nq * 4; e < E; ++e)
            out[e] = dot16(hh, src[e], dst[e]);
    }
}

// Fallback (ws too small): original fp32 gather kernel.
__global__ __launch_bounds__(256) void edge_dot_fp32(
    const float4* __restrict__ h,
    const int* __restrict__ src,
    const int* __restrict__ dst,
    float* __restrict__ out,
    int E)
{
    int idx = blockIdx.x * blockDim.x + threadIdx.x;
    int stride = gridDim.x * blockDim.x;
    for (int e = idx; e < E; e += stride) {
        int s = src[e];
        int d = dst[e];
        const float4* hs = h + (size_t)s * 4;
        const float4* hd = h + (size_t)d * 4;
        float acc = 0.0f;
#pragma unroll
        for (int k = 0; k < 4; ++k) {
            float4 a = hs[k];
            float4 b = hd[k];
            acc += a.x * b.x + a.y * b.y + a.z * b.z + a.w * b.w;
        }
        out[e] = acc;
    }
}

extern "C" void kernel_launch(void* const* d_in, const int* in_sizes, int n_in,
                              void* d_out, int out_size, void* d_ws, size_t ws_size,
                              hipStream_t stream) {
    const float* h   = (const float*)d_in[0];   // [N, 16] fp32
    const int*   src = (const int*)d_in[1];     // [E] int32
    const int*   dst = (const int*)d_in[2];     // [E]
    float*       out = (float*)d_out;           // [E]

    const int N = in_sizes[0] / 16;
    const int E = in_sizes[1];

    const size_t need = (size_t)N * 16 * sizeof(__half);  // 3.2 MB
    if (ws_size >= need) {
        uint4* hh = (uint4*)d_ws;
        // Phase 1: fp32 -> fp16 table
        int n_out = N * 2;  // uint4 count
        convert_h_fp16<<<(n_out + 255) / 256, 256, 0, stream>>>(
            (const float4*)h, hh, n_out);
        // Phase 2: edge dots
        int nq = E / 4;
        int grid = (nq + 255) / 256;
        edge_dot_fp16<<<grid, 256, 0, stream>>>(
            (const uint4*)hh, (const int4*)src, (const int4*)dst, (float4*)out,
            nq, src, dst, out, E);
    } else {
        int grid = (E + 255) / 256;
        if (grid > 2048) grid = 2048;
        edge_dot_fp32<<<grid, 256, 0, stream>>>(
            (const float4*)h, src, dst, out, E);
    }
}

// Round 3
// 41.687 us; speedup vs baseline: 2.3345x; 1.0681x over previous
//
#include <hip/hip_runtime.h>
#include <hip/hip_bf16.h>
#include <hip/hip_fp16.h>

// Phase 1: convert h (fp32, [N,16]) -> fp16 table in workspace ([N,16] halfs,
// 32 B/row). 3.2 MB fits per-XCD L2 (4 MB); fp32 table (6.4 MB) thrashed it.
__global__ __launch_bounds__(256) void convert_h_fp16(
    const float4* __restrict__ h4,   // [N*4] float4
    uint4* __restrict__ hh,          // [N*2] uint4 (8 halfs each)
    int n_out)                       // N*2
{
    int i = blockIdx.x * blockDim.x + threadIdx.x;
    if (i >= n_out) return;
    float4 a = h4[2 * i];
    float4 b = h4[2 * i + 1];
    __half2 p[4];
    p[0] = __floats2half2_rn(a.x, a.y);
    p[1] = __floats2half2_rn(a.z, a.w);
    p[2] = __floats2half2_rn(b.x, b.y);
    p[3] = __floats2half2_rn(b.z, b.w);
    hh[i] = *reinterpret_cast<const uint4*>(p);
}

__device__ __forceinline__ float dot2u(unsigned a, unsigned b) {
    __half2 ha = *reinterpret_cast<const __half2*>(&a);
    __half2 hb = *reinterpret_cast<const __half2*>(&b);
    float2 fa = __half22float2(ha);
    float2 fb = __half22float2(hb);
    return fa.x * fb.x + fa.y * fb.y;
}

__device__ __forceinline__ float dot8u(uint4 a, uint4 b) {
    return dot2u(a.x, b.x) + dot2u(a.y, b.y) + dot2u(a.z, b.z) + dot2u(a.w, b.w);
}

__device__ __forceinline__ float dot16(const uint4* __restrict__ hh, int s, int d) {
    uint4 a0 = hh[(size_t)s * 2];
    uint4 a1 = hh[(size_t)s * 2 + 1];
    uint4 b0 = hh[(size_t)d * 2];
    uint4 b1 = hh[(size_t)d * 2 + 1];
    return dot8u(a0, b0) + dot8u(a1, b1);
}

// Phase 2: LANE-PAIR per edge group. Lanes 2i/2i+1 each load one 16B half of
// the same 32B row -> the coalescer merges them into ONE L2 transaction
// (2 txns/edge instead of 4). Partial dots combined via shfl_xor(1).
// Each pair handles 4 edges per iteration (int4 index loads, broadcast).
__global__ __launch_bounds__(256) void edge_dot_pair(
    const uint4* __restrict__ hh,    // [N*2] (row = 2 x uint4)
    const int4* __restrict__ src4,   // [E/4]
    const int4* __restrict__ dst4,   // [E/4]
    float2* __restrict__ out2,       // [E/2]
    int nq,                          // E/4
    const int* __restrict__ src,     // scalar views for tail
    const int* __restrict__ dst,
    float* __restrict__ out,
    int E)
{
    int tid = blockIdx.x * blockDim.x + threadIdx.x;
    int half = tid & 1;              // which 16B half of each row this lane owns
    int pair = tid >> 1;
    int pstride = (gridDim.x * blockDim.x) >> 1;

    for (int q = pair; q < nq; q += pstride) {
        int4 s4 = src4[q];           // broadcast within the pair
        int4 d4 = dst4[q];
        int ss[4] = {s4.x, s4.y, s4.z, s4.w};
        int dd[4] = {d4.x, d4.y, d4.z, d4.w};
        float r[4];
#pragma unroll
        for (int k = 0; k < 4; ++k) {
            uint4 a = hh[(size_t)ss[k] * 2 + half];
            uint4 b = hh[(size_t)dd[k] * 2 + half];
            float partial = dot8u(a, b);
            r[k] = partial + __shfl_xor(partial, 1, 64);
        }
        // Pair stores the 4 results as two adjacent float2 (16B coalesced).
        float2 v;
        v.x = half ? r[2] : r[0];
        v.y = half ? r[3] : r[1];
        out2[(size_t)q * 2 + half] = v;
    }

    // tail (E % 4 != 0)
    if (tid == 0) {
        for (int e = nq * 4; e < E; ++e)
            out[e] = dot16(hh, src[e], dst[e]);
    }
}

// Fallback (ws too small): fp32 gather kernel.
__global__ __launch_bounds__(256) void edge_dot_fp32(
    const float4* __restrict__ h,
    const int* __restrict__ src,
    const int* __restrict__ dst,
    float* __restrict__ out,
    int E)
{
    int idx = blockIdx.x * blockDim.x + threadIdx.x;
    int stride = gridDim.x * blockDim.x;
    for (int e = idx; e < E; e += stride) {
        int s = src[e];
        int d = dst[e];
        const float4* hs = h + (size_t)s * 4;
        const float4* hd = h + (size_t)d * 4;
        float acc = 0.0f;
#pragma unroll
        for (int k = 0; k < 4; ++k) {
            float4 a = hs[k];
            float4 b = hd[k];
            acc += a.x * b.x + a.y * b.y + a.z * b.z + a.w * b.w;
        }
        out[e] = acc;
    }
}

extern "C" void kernel_launch(void* const* d_in, const int* in_sizes, int n_in,
                              void* d_out, int out_size, void* d_ws, size_t ws_size,
                              hipStream_t stream) {
    const float* h   = (const float*)d_in[0];   // [N, 16] fp32
    const int*   src = (const int*)d_in[1];     // [E] int32
    const int*   dst = (const int*)d_in[2];     // [E]
    float*       out = (float*)d_out;           // [E]

    const int N = in_sizes[0] / 16;
    const int E = in_sizes[1];

    const size_t need = (size_t)N * 16 * sizeof(__half);  // 3.2 MB
    if (ws_size >= need) {
        uint4* hh = (uint4*)d_ws;
        int n_out = N * 2;
        convert_h_fp16<<<(n_out + 255) / 256, 256, 0, stream>>>(
            (const float4*)h, hh, n_out);

        int nq = E / 4;
        // 2 threads per edge-group-of-4; full grid, 1 iteration typical.
        long long threads = (long long)nq * 2;
        int grid = (int)((threads + 255) / 256);
        if (grid < 1) grid = 1;
        edge_dot_pair<<<grid, 256, 0, stream>>>(
            (const uint4*)hh, (const int4*)src, (const int4*)dst, (float2*)out,
            nq, src, dst, out, E);
    } else {
        int grid = (E + 255) / 256;
        if (grid > 2048) grid = 2048;
        edge_dot_fp32<<<grid, 256, 0, stream>>>(
            (const float4*)h, src, dst, out, E);
    }
}